// Round 5
// baseline (731.977 us; speedup 1.0000x reference)
//
#include <hip/hip_runtime.h>

typedef unsigned short ushort_t;
typedef unsigned int uint_t;
typedef __attribute__((ext_vector_type(8))) __bf16 bf16x8;
typedef __attribute__((ext_vector_type(4))) float f32x4;
typedef __attribute__((ext_vector_type(4))) uint_t uint4v;

#define NN 160000
#define DD 128
#define EE 600000
#define RR 8
#define NRR (NN * RR)          // 1,280,000 pairs
#define CAP1 486000            // compact-row cap (mean ~479.1K, +13 sigma)

__device__ __forceinline__ ushort_t f2b(float f) {
  uint_t u = __float_as_uint(f);
  u = u + 0x7fffu + ((u >> 16) & 1u);   // round-nearest-even
  return (ushort_t)(u >> 16);
}
__device__ __forceinline__ float b2f(ushort_t u) {
  return __uint_as_float(((uint_t)u) << 16);
}

// ---------------- weight convert + transpose: src [nmat][K][128] f32 -> dst [nmat][128][K] bf16 ----------------
__global__ void wconv_kernel(const float* __restrict__ src,
                             ushort_t* __restrict__ dst, int K, int nmat) {
  int i = blockIdx.x * blockDim.x + threadIdx.x;
  int total = nmat * K * 128;
  if (i >= total) return;
  int m = i / (K * 128), rem = i % (K * 128);
  int k = rem / 128, n = rem % 128;
  dst[(size_t)m * 128 * K + (size_t)n * K + k] = f2b(src[i]);
}

// ---------------- projection GEMM: C[M x 128](bf16) = A[M x K](f32) @ WT[128 x K](bf16) ----------------
__global__ __launch_bounds__(256, 2) void gemm_proj(
    const float* __restrict__ Ain, const ushort_t* __restrict__ WT,
    const float* __restrict__ bias, ushort_t* __restrict__ Cout, int M, int K) {
  __shared__ ushort_t As[128 * 128];
  __shared__ ushort_t Ws[128 * 128];
  const int tid = threadIdx.x;
  const int bm = blockIdx.x * 128;
  const int wave = tid >> 6, lane = tid & 63;
  const int lr = lane & 15;
  const int lg = lane >> 4;

  f32x4 acc[2][8];
#pragma unroll
  for (int mt = 0; mt < 2; ++mt)
#pragma unroll
    for (int nt = 0; nt < 8; ++nt) acc[mt][nt] = {0.f, 0.f, 0.f, 0.f};

  for (int k0 = 0; k0 < K; k0 += 128) {
#pragma unroll
    for (int it = 0; it < 8; ++it) {
      int row = it * 16 + (tid >> 4);
      int c = tid & 15;
      uint4v val = {0, 0, 0, 0};
      int grow = bm + row, gk = k0 + c * 8;
      if (grow < M && gk < K) {
        const float* ap = Ain + (size_t)grow * K + gk;
        float4 v0 = *(const float4*)ap;
        float4 v1 = *(const float4*)(ap + 4);
        val[0] = (uint_t)f2b(v0.x) | ((uint_t)f2b(v0.y) << 16);
        val[1] = (uint_t)f2b(v0.z) | ((uint_t)f2b(v0.w) << 16);
        val[2] = (uint_t)f2b(v1.x) | ((uint_t)f2b(v1.y) << 16);
        val[3] = (uint_t)f2b(v1.z) | ((uint_t)f2b(v1.w) << 16);
      }
      *(uint4v*)&As[row * 128 + ((c ^ (row & 7)) * 8)] = val;
    }
#pragma unroll
    for (int it = 0; it < 8; ++it) {
      int n = it * 16 + (tid >> 4);
      int c = tid & 15;
      uint4v val = {0, 0, 0, 0};
      int gk = k0 + c * 8;
      if (gk < K)
        val = *(const uint4v*)(WT + (size_t)n * K + gk);
      *(uint4v*)&Ws[n * 128 + ((c ^ (n & 7)) * 8)] = val;
    }
    __syncthreads();
#pragma unroll
    for (int ks = 0; ks < 4; ++ks) {
      int chunk = ks * 4 + lg;
      bf16x8 af[2], bfr[8];
#pragma unroll
      for (int mt = 0; mt < 2; ++mt) {
        int row = wave * 32 + mt * 16 + lr;
        af[mt] = *(const bf16x8*)&As[row * 128 + ((chunk ^ (row & 7)) * 8)];
      }
#pragma unroll
      for (int nt = 0; nt < 8; ++nt) {
        int n = nt * 16 + lr;
        bfr[nt] = *(const bf16x8*)&Ws[n * 128 + ((chunk ^ (n & 7)) * 8)];
      }
#pragma unroll
      for (int mt = 0; mt < 2; ++mt)
#pragma unroll
        for (int nt = 0; nt < 8; ++nt)
          acc[mt][nt] = __builtin_amdgcn_mfma_f32_16x16x32_bf16(
              af[mt], bfr[nt], acc[mt][nt], 0, 0, 0);
    }
    __syncthreads();
  }

  float bv[8];
#pragma unroll
  for (int nt = 0; nt < 8; ++nt) bv[nt] = bias[nt * 16 + lr];

#pragma unroll
  for (int mt = 0; mt < 2; ++mt) {
    int rbase = bm + wave * 32 + mt * 16 + lg * 4;
#pragma unroll
    for (int i = 0; i < 4; ++i) {
      int row = rbase + i;
      if (row >= M) continue;
#pragma unroll
      for (int nt = 0; nt < 8; ++nt)
        Cout[(size_t)row * 128 + nt * 16 + lr] = f2b(acc[mt][nt][i] + bv[nt]);
    }
  }
}

// ---------------- fused aggregate + per-relation GEMM ----------------
// A-tile rows are (rel,dst) pair means gathered directly from xb; C -> tC (bf16).
__global__ __launch_bounds__(256, 2) void gemm_rel_agg(
    const ushort_t* __restrict__ xb, const int* __restrict__ segrow,
    const int* __restrict__ sorted_src, const int* __restrict__ rowstart,
    const ushort_t* __restrict__ WT_all, ushort_t* __restrict__ tC) {
  __shared__ ushort_t As[128 * 128];
  __shared__ ushort_t Ws[128 * 128];
  const int rel = blockIdx.y;
  const int start = rowstart[rel], end = rowstart[rel + 1];
  const int bm = start + blockIdx.x * 128;
  if (bm >= end) return;
  const ushort_t* WT = WT_all + (size_t)rel * 16384;
  const int tid = threadIdx.x;
  const int wave = tid >> 6, lane = tid & 63;
  const int lr = lane & 15, lg = lane >> 4;

  // stage A: per-pair mean gathered from xb
#pragma unroll
  for (int it = 0; it < 8; ++it) {
    int row16 = it * 16 + (tid >> 4);
    int sl = tid & 15;
    int g = bm + row16;
    uint4v o = {0, 0, 0, 0};
    if (g < end) {
      int s0 = segrow[g], s1 = segrow[g + 1];
      float a[8];
#pragma unroll
      for (int j = 0; j < 8; ++j) a[j] = 0.f;
      for (int i = s0; i < s1; ++i) {
        int s = sorted_src[i];
        uint4v v = *(const uint4v*)(xb + (size_t)s * DD + sl * 8);
#pragma unroll
        for (int j = 0; j < 4; ++j) {
          a[j * 2]     += b2f((ushort_t)(v[j] & 0xffff));
          a[j * 2 + 1] += b2f((ushort_t)(v[j] >> 16));
        }
      }
      float sc = 1.0f / (float)(s1 - s0);
#pragma unroll
      for (int j = 0; j < 4; ++j)
        o[j] = (uint_t)f2b(a[j * 2] * sc) | ((uint_t)f2b(a[j * 2 + 1] * sc) << 16);
    }
    *(uint4v*)&As[row16 * 128 + ((sl ^ (row16 & 7)) * 8)] = o;
  }
#pragma unroll
  for (int it = 0; it < 8; ++it) {
    int n = it * 16 + (tid >> 4);
    int cc = tid & 15;
    uint4v val = *(const uint4v*)(WT + (size_t)n * 128 + cc * 8);
    *(uint4v*)&Ws[n * 128 + ((cc ^ (n & 7)) * 8)] = val;
  }
  __syncthreads();

  f32x4 acc[2][8];
#pragma unroll
  for (int mt = 0; mt < 2; ++mt)
#pragma unroll
    for (int nt = 0; nt < 8; ++nt) acc[mt][nt] = {0.f, 0.f, 0.f, 0.f};

#pragma unroll
  for (int ks = 0; ks < 4; ++ks) {
    int chunk = ks * 4 + lg;
    bf16x8 af[2], bfr[8];
#pragma unroll
    for (int mt = 0; mt < 2; ++mt) {
      int row = wave * 32 + mt * 16 + lr;
      af[mt] = *(const bf16x8*)&As[row * 128 + ((chunk ^ (row & 7)) * 8)];
    }
#pragma unroll
    for (int nt = 0; nt < 8; ++nt) {
      int n = nt * 16 + lr;
      bfr[nt] = *(const bf16x8*)&Ws[n * 128 + ((chunk ^ (n & 7)) * 8)];
    }
#pragma unroll
    for (int mt = 0; mt < 2; ++mt)
#pragma unroll
      for (int nt = 0; nt < 8; ++nt)
        acc[mt][nt] = __builtin_amdgcn_mfma_f32_16x16x32_bf16(
            af[mt], bfr[nt], acc[mt][nt], 0, 0, 0);
  }

#pragma unroll
  for (int mt = 0; mt < 2; ++mt) {
    int rbase = bm + wave * 32 + mt * 16 + lg * 4;
#pragma unroll
    for (int i = 0; i < 4; ++i) {
      int row = rbase + i;
      if (row >= end) continue;
#pragma unroll
      for (int nt = 0; nt < 8; ++nt)
        tC[(size_t)row * 128 + nt * 16 + lr] = f2b(acc[mt][nt][i]);
    }
  }
}

// ---------------- fused root GEMM + combine ----------------
// C = xb@rootT + bias + sum_r tC[rowidT[dst][r]]; RELU_BF: relu+bf16 -> xbout (in-place ok),
// else f32 -> fout.  Grid must be exactly NN/128 blocks.
template <bool RELU_BF>
__global__ __launch_bounds__(256, 2) void gemm_root_combine(
    const ushort_t* __restrict__ Axb, const ushort_t* __restrict__ WT,
    const float* __restrict__ bias, const int* __restrict__ rowidT,
    const ushort_t* __restrict__ tC, float* __restrict__ fout,
    ushort_t* __restrict__ xbout) {
  __shared__ ushort_t smem[2 * 128 * 128];   // 64 KB: As|Ws, reused as f32 Cs
  ushort_t* As = smem;
  ushort_t* Ws = smem + 128 * 128;
  const int tid = threadIdx.x;
  const int bm = blockIdx.x * 128;
  const int wave = tid >> 6, lane = tid & 63;
  const int lr = lane & 15, lg = lane >> 4;

#pragma unroll
  for (int it = 0; it < 8; ++it) {
    int row = it * 16 + (tid >> 4);
    int c = tid & 15;
    uint4v val = *(const uint4v*)(Axb + (size_t)(bm + row) * 128 + c * 8);
    *(uint4v*)&As[row * 128 + ((c ^ (row & 7)) * 8)] = val;
  }
#pragma unroll
  for (int it = 0; it < 8; ++it) {
    int n = it * 16 + (tid >> 4);
    int c = tid & 15;
    uint4v val = *(const uint4v*)(WT + (size_t)n * 128 + c * 8);
    *(uint4v*)&Ws[n * 128 + ((c ^ (n & 7)) * 8)] = val;
  }
  __syncthreads();

  f32x4 acc[2][8];
#pragma unroll
  for (int mt = 0; mt < 2; ++mt)
#pragma unroll
    for (int nt = 0; nt < 8; ++nt) acc[mt][nt] = {0.f, 0.f, 0.f, 0.f};

#pragma unroll
  for (int ks = 0; ks < 4; ++ks) {
    int chunk = ks * 4 + lg;
    bf16x8 af[2], bfr[8];
#pragma unroll
    for (int mt = 0; mt < 2; ++mt) {
      int row = wave * 32 + mt * 16 + lr;
      af[mt] = *(const bf16x8*)&As[row * 128 + ((chunk ^ (row & 7)) * 8)];
    }
#pragma unroll
    for (int nt = 0; nt < 8; ++nt) {
      int n = nt * 16 + lr;
      bfr[nt] = *(const bf16x8*)&Ws[n * 128 + ((chunk ^ (n & 7)) * 8)];
    }
#pragma unroll
    for (int mt = 0; mt < 2; ++mt)
#pragma unroll
      for (int nt = 0; nt < 8; ++nt)
        acc[mt][nt] = __builtin_amdgcn_mfma_f32_16x16x32_bf16(
            af[mt], bfr[nt], acc[mt][nt], 0, 0, 0);
  }
  __syncthreads();   // done reading As/Ws

  // park C (+bias) in LDS as f32
  float* Cs = (float*)smem;
  float bv[8];
#pragma unroll
  for (int nt = 0; nt < 8; ++nt) bv[nt] = bias[nt * 16 + lr];
#pragma unroll
  for (int mt = 0; mt < 2; ++mt) {
    int rl = wave * 32 + mt * 16 + lg * 4;
#pragma unroll
    for (int i = 0; i < 4; ++i)
#pragma unroll
      for (int nt = 0; nt < 8; ++nt)
        Cs[(rl + i) * 128 + nt * 16 + lr] = acc[mt][nt][i] + bv[nt];
  }
  __syncthreads();

  // combine: each wave owns 32 dst rows
  for (int rr = 0; rr < 32; ++rr) {
    int rl = wave * 32 + rr;
    int dstn = bm + rl;
    const int* rt = rowidT + (size_t)dstn * 8;
    int4 ra = *(const int4*)rt;
    int4 rb = *(const int4*)(rt + 4);
    float2 v = ((const float2*)(Cs + (size_t)rl * 128))[lane];
    int rw[8] = {ra.x, ra.y, ra.z, ra.w, rb.x, rb.y, rb.z, rb.w};
#pragma unroll
    for (int r = 0; r < 8; ++r) {
      if (rw[r] >= 0) {
        uint_t t = ((const uint_t*)(tC + (size_t)rw[r] * 128))[lane];
        v.x += b2f((ushort_t)(t & 0xffff));
        v.y += b2f((ushort_t)(t >> 16));
      }
    }
    if (RELU_BF) {
      uint_t o = (uint_t)f2b(fmaxf(v.x, 0.f)) | ((uint_t)f2b(fmaxf(v.y, 0.f)) << 16);
      ((uint_t*)(xbout + (size_t)dstn * 128))[lane] = o;
    } else {
      ((float2*)(fout + (size_t)dstn * 128))[lane] = v;
    }
  }
}

// ---------------- edge bucketing ----------------
__global__ void count_kernel(const int* __restrict__ dstv, const int* __restrict__ et,
                             int* __restrict__ cnt, int E) {
  int e = blockIdx.x * blockDim.x + threadIdx.x;
  if (e < E) atomicAdd(&cnt[(size_t)et[e] * NN + dstv[e]], 1);
}

__global__ __launch_bounds__(256) void scan1_kernel(const int* __restrict__ in, int* __restrict__ out,
                                                    int* __restrict__ partials, int n, int binarize) {
  __shared__ int sums[256];
  int tid = threadIdx.x;
  int base = blockIdx.x * 2048 + tid * 8;
  int v[8];
  int s = 0;
#pragma unroll
  for (int i = 0; i < 8; ++i) {
    int idx = base + i;
    int x = (idx < n) ? in[idx] : 0;
    if (binarize) x = (x > 0) ? 1 : 0;
    v[i] = s;
    s += x;
  }
  sums[tid] = s;
  __syncthreads();
  for (int off = 1; off < 256; off <<= 1) {
    int t = (tid >= off) ? sums[tid - off] : 0;
    __syncthreads();
    sums[tid] += t;
    __syncthreads();
  }
  int excl = (tid == 0) ? 0 : sums[tid - 1];
  if (tid == 255) partials[blockIdx.x] = sums[255];
#pragma unroll
  for (int i = 0; i < 8; ++i) {
    int idx = base + i;
    if (idx < n) out[idx] = excl + v[i];
  }
}

__global__ __launch_bounds__(256) void scan2_kernel(int* __restrict__ partials, int nb) {
  __shared__ int sums[256];
  int tid = threadIdx.x;
  int per = (nb + 255) / 256;
  int start = tid * per;
  int s = 0;
  for (int i = 0; i < per; ++i) {
    int idx = start + i;
    if (idx < nb) s += partials[idx];
  }
  sums[tid] = s;
  __syncthreads();
  for (int off = 1; off < 256; off <<= 1) {
    int t = (tid >= off) ? sums[tid - off] : 0;
    __syncthreads();
    sums[tid] += t;
    __syncthreads();
  }
  int excl = (tid == 0) ? 0 : sums[tid - 1];
  for (int i = 0; i < per; ++i) {
    int idx = start + i;
    if (idx < nb) {
      int t = partials[idx];
      partials[idx] = excl;
      excl += t;
    }
  }
}

__global__ void scan3_kernel(int* __restrict__ out, const int* __restrict__ partials, int n) {
  int base = blockIdx.x * 2048 + threadIdx.x * 8;
  int add = partials[blockIdx.x];
#pragma unroll
  for (int i = 0; i < 8; ++i) {
    int idx = base + i;
    if (idx < n) out[idx] += add;
  }
}

__global__ void finalize_kernel(const int* __restrict__ cnt, int* __restrict__ seg_off,
                                const int* __restrict__ rowid, int* __restrict__ rowstart,
                                int* __restrict__ segrow) {
  int t = threadIdx.x;
  if (t == 0) seg_off[NRR] = EE;
  if (t < 8) rowstart[t] = rowid[(size_t)t * NN];
  if (t == 8) {
    int rs8 = rowid[NRR - 1] + (cnt[NRR - 1] > 0 ? 1 : 0);
    rowstart[8] = rs8;
    segrow[rs8] = EE;
  }
}

// rowidT[dst][rel] = compact row or -1; segrow[row] = edge-segment start
__global__ void build_kernel(const int* __restrict__ cnt, const int* __restrict__ rowid,
                             const int* __restrict__ seg_off, int* __restrict__ rowidT,
                             int* __restrict__ segrow) {
  int p = blockIdx.x * blockDim.x + threadIdx.x;
  if (p >= NRR) return;
  int rel = p / NN, dstn = p - rel * NN;
  bool act = cnt[p] > 0;
  int rw = rowid[p];
  rowidT[(size_t)dstn * 8 + rel] = act ? rw : -1;
  if (act) segrow[rw] = seg_off[p];
}

__global__ void place_kernel(const int* __restrict__ srcv, const int* __restrict__ dstv,
                             const int* __restrict__ et, const int* __restrict__ seg_off,
                             int* __restrict__ cursor, int* __restrict__ sorted_src, int E) {
  int e = blockIdx.x * blockDim.x + threadIdx.x;
  if (e < E) {
    int p = et[e] * NN + dstv[e];
    int slot = seg_off[p] + atomicAdd(&cursor[p], 1);
    sorted_src[slot] = srcv[e];
  }
}

static inline void launch_proj(const float* A, const ushort_t* WT, const float* bias,
                               ushort_t* C, int M, int K, hipStream_t stream) {
  hipLaunchKernelGGL(gemm_proj, dim3((M + 127) / 128), dim3(256), 0, stream,
                     A, WT, bias, C, M, K);
}
static inline void launch_wconv(const float* s, ushort_t* d, int K, int nmat, hipStream_t stream) {
  int total = nmat * K * 128;
  hipLaunchKernelGGL(wconv_kernel, dim3((total + 255) / 256), dim3(256), 0, stream, s, d, K, nmat);
}
static inline void launch_scan(const int* in, int* out, int* partials, int n, int binarize,
                               hipStream_t stream) {
  int nb = (n + 2047) / 2048;
  hipLaunchKernelGGL(scan1_kernel, dim3(nb), dim3(256), 0, stream, in, out, partials, n, binarize);
  hipLaunchKernelGGL(scan2_kernel, dim3(1), dim3(256), 0, stream, partials, nb);
  hipLaunchKernelGGL(scan3_kernel, dim3(nb), dim3(256), 0, stream, out, partials, n);
}

extern "C" void kernel_launch(void* const* d_in, const int* in_sizes, int n_in,
                              void* d_out, int out_size, void* d_ws, size_t ws_size,
                              hipStream_t stream) {
  const float* x_user = (const float*)d_in[0];
  const float* x_food = (const float*)d_in[1];
  const float* x_ing  = (const float*)d_in[2];
  const float* x_cat  = (const float*)d_in[3];
  const float* x_hab  = (const float*)d_in[4];
  const int*   eidx   = (const int*)d_in[5];
  const int*   etype  = (const int*)d_in[6];
  const float* Wu = (const float*)d_in[7];
  const float* bu = (const float*)d_in[8];
  const float* Wf = (const float*)d_in[9];
  const float* bfp = (const float*)d_in[10];
  const float* Wi = (const float*)d_in[11];
  const float* bi = (const float*)d_in[12];
  const float* Wc = (const float*)d_in[13];
  const float* bc = (const float*)d_in[14];
  const float* Wh = (const float*)d_in[15];
  const float* bh = (const float*)d_in[16];
  const float* W1    = (const float*)d_in[17];
  const float* root1 = (const float*)d_in[18];
  const float* bias1 = (const float*)d_in[19];
  const float* W2    = (const float*)d_in[20];
  const float* root2 = (const float*)d_in[21];
  const float* bias2 = (const float*)d_in[22];

  const int* src = eidx;
  const int* dst = eidx + EE;

  // ---- workspace layout (~176 MB; bucketing temps aliased inside tC) ----
  char* ws = (char*)d_ws;
  ushort_t* xb  = (ushort_t*)(ws);                       // 40,960,000 B
  ushort_t* tC  = (ushort_t*)(ws + 40960000);            // 124,416,000 B (CAP1 rows)
  int* seg_off  = (int*)(ws + 40960000);                 // alias in tC: 5,120,064 B
  int* rowid    = (int*)(ws + 40960000 + 5120064);       // alias in tC: 5,120,000 B
  int* cnt_i    = (int*)(ws + 40960000 + 10240064);      // alias in tC: 5,120,000 B (also cursor)
  int* segrow   = (int*)(ws + 165376000);                // (CAP1+1)*4 -> 1,944,064 B
  int* rowidT   = (int*)(ws + 167320064);                // NRR*4 = 5,120,000 B
  int* sorted_src = (int*)(ws + 172440064);              // EE*4 = 2,400,000 B
  int* rowstart   = (int*)(ws + 174840064);              // 64 B
  int* partials   = (int*)(ws + 174840128);              // 4,096 B
  ushort_t* wbuf  = (ushort_t*)(ws + 174844224);         // 753,664 B

  ushort_t* WuT = wbuf;            // 128x256
  ushort_t* WfT = wbuf + 32768;    // 128x128
  ushort_t* WiT = wbuf + 49152;
  ushort_t* WcT = wbuf + 65536;    // 128x64
  ushort_t* WhT = wbuf + 73728;
  ushort_t* r1T = wbuf + 81920;    // 128x128
  ushort_t* r2T = wbuf + 98304;
  ushort_t* W1T = wbuf + 114688;   // 8 x 128x128
  ushort_t* W2T = wbuf + 245760;

  float* out = (float*)d_out;

  // ---- weight conversion + transpose ----
  launch_wconv(Wu, WuT, 256, 1, stream);
  launch_wconv(Wf, WfT, 128, 1, stream);
  launch_wconv(Wi, WiT, 128, 1, stream);
  launch_wconv(Wc, WcT, 64, 1, stream);
  launch_wconv(Wh, WhT, 64, 1, stream);
  launch_wconv(root1, r1T, 128, 1, stream);
  launch_wconv(root2, r2T, 128, 1, stream);
  launch_wconv(W1, W1T, 128, 8, stream);
  launch_wconv(W2, W2T, 128, 8, stream);

  // ---- input projections -> xb (bf16 x_all) ----
  launch_proj(x_user, WuT, bu, xb + (size_t)0 * DD,      50000, 256, stream);
  launch_proj(x_food, WfT, bfp, xb + (size_t)50000 * DD, 50000, 128, stream);
  launch_proj(x_ing,  WiT, bi, xb + (size_t)100000 * DD, 50000, 128, stream);
  launch_proj(x_cat,  WcT, bc, xb + (size_t)150000 * DD, 5000,  64,  stream);
  launch_proj(x_hab,  WhT, bh, xb + (size_t)155000 * DD, 5000,  64,  stream);

  // ---- bucket edges by (relation, dst); build segrow / rowidT / rowstart ----
  hipMemsetAsync(cnt_i, 0, (size_t)NRR * 4, stream);
  hipLaunchKernelGGL(count_kernel, dim3((EE + 255) / 256), dim3(256), 0, stream,
                     dst, etype, cnt_i, EE);
  launch_scan(cnt_i, seg_off, partials, NRR, 0, stream);
  launch_scan(cnt_i, rowid, partials, NRR, 1, stream);
  hipLaunchKernelGGL(finalize_kernel, dim3(1), dim3(64), 0, stream,
                     cnt_i, seg_off, rowid, rowstart, segrow);
  hipLaunchKernelGGL(build_kernel, dim3((NRR + 255) / 256), dim3(256), 0, stream,
                     cnt_i, rowid, seg_off, rowidT, segrow);
  hipMemsetAsync(cnt_i, 0, (size_t)NRR * 4, stream);  // reuse as cursor
  hipLaunchKernelGGL(place_kernel, dim3((EE + 255) / 256), dim3(256), 0, stream,
                     src, dst, etype, seg_off, cnt_i, sorted_src, EE);

  const dim3 relGrid(512, RR);
  const dim3 rootGrid(NN / 128);   // 1250, exact

  // ---- conv1: tC = mean@W1; xb = relu(xb@root1 + bias1 + combine) in place ----
  hipLaunchKernelGGL(gemm_rel_agg, relGrid, dim3(256), 0, stream,
                     xb, segrow, sorted_src, rowstart, W1T, tC);
  hipLaunchKernelGGL((gemm_root_combine<true>), rootGrid, dim3(256), 0, stream,
                     xb, r1T, bias1, rowidT, tC, (float*)nullptr, xb);

  // ---- conv2: tC = mean@W2; d_out = xb@root2 + bias2 + combine (f32) ----
  hipLaunchKernelGGL(gemm_rel_agg, relGrid, dim3(256), 0, stream,
                     xb, segrow, sorted_src, rowstart, W2T, tC);
  hipLaunchKernelGGL((gemm_root_combine<false>), rootGrid, dim3(256), 0, stream,
                     xb, r2T, bias2, rowidT, tC, out, (ushort_t*)nullptr);
}

// Round 6
// 576.500 us; speedup vs baseline: 1.2697x; 1.2697x over previous
//
#include <hip/hip_runtime.h>

typedef unsigned short ushort_t;
typedef unsigned int uint_t;
typedef __attribute__((ext_vector_type(8))) __bf16 bf16x8;
typedef __attribute__((ext_vector_type(4))) float f32x4;
typedef __attribute__((ext_vector_type(4))) uint_t uint4v;

#define NN 160000
#define DD 128
#define EE 600000
#define RR 8
#define NRR (NN * RR)          // 1,280,000 pairs
#define CAP1 486000            // compact-row cap (mean ~479.1K, +13 sigma)
#define WTOT 376832            // total bf16 weight elements

__device__ __forceinline__ ushort_t f2b(float f) {
  uint_t u = __float_as_uint(f);
  u = u + 0x7fffu + ((u >> 16) & 1u);   // round-nearest-even
  return (ushort_t)(u >> 16);
}
__device__ __forceinline__ float b2f(ushort_t u) {
  return __uint_as_float(((uint_t)u) << 16);
}

// ---------------- merged weight convert+transpose for all 9 matrices ----------------
struct WSrcs { const float* s[9]; };

__global__ void wconv_all_kernel(WSrcs srcs, ushort_t* __restrict__ wbuf) {
  int i = blockIdx.x * blockDim.x + threadIdx.x;
  if (i >= WTOT) return;
  int m, start, K;
  if      (i < 32768)  { m = 0; start = 0;      K = 256; }
  else if (i < 49152)  { m = 1; start = 32768;  K = 128; }
  else if (i < 65536)  { m = 2; start = 49152;  K = 128; }
  else if (i < 73728)  { m = 3; start = 65536;  K = 64;  }
  else if (i < 81920)  { m = 4; start = 73728;  K = 64;  }
  else if (i < 98304)  { m = 5; start = 81920;  K = 128; }
  else if (i < 114688) { m = 6; start = 98304;  K = 128; }
  else if (i < 245760) { m = 7; start = 114688; K = 128; }
  else                 { m = 8; start = 245760; K = 128; }
  int local = i - start;
  int per = K * 128;
  int mat = local / per, rem = local - mat * per;
  int k = rem >> 7, n = rem & 127;
  wbuf[start + mat * per + n * K + k] = f2b(srcs.s[m][local]);
}

// ---------------- projection GEMM: C[M x 128](bf16) = A[M x K](f32) @ WT[128 x K](bf16) ----------------
__global__ __launch_bounds__(256, 2) void gemm_proj(
    const float* __restrict__ Ain, const ushort_t* __restrict__ WT,
    const float* __restrict__ bias, ushort_t* __restrict__ Cout, int M, int K) {
  __shared__ ushort_t As[128 * 128];
  __shared__ ushort_t Ws[128 * 128];
  const int tid = threadIdx.x;
  const int bm = blockIdx.x * 128;
  const int wave = tid >> 6, lane = tid & 63;
  const int lr = lane & 15;
  const int lg = lane >> 4;

  f32x4 acc[2][8];
#pragma unroll
  for (int mt = 0; mt < 2; ++mt)
#pragma unroll
    for (int nt = 0; nt < 8; ++nt) acc[mt][nt] = {0.f, 0.f, 0.f, 0.f};

  for (int k0 = 0; k0 < K; k0 += 128) {
#pragma unroll
    for (int it = 0; it < 8; ++it) {
      int row = it * 16 + (tid >> 4);
      int c = tid & 15;
      uint4v val = {0, 0, 0, 0};
      int grow = bm + row, gk = k0 + c * 8;
      if (grow < M && gk < K) {
        const float* ap = Ain + (size_t)grow * K + gk;
        float4 v0 = *(const float4*)ap;
        float4 v1 = *(const float4*)(ap + 4);
        val[0] = (uint_t)f2b(v0.x) | ((uint_t)f2b(v0.y) << 16);
        val[1] = (uint_t)f2b(v0.z) | ((uint_t)f2b(v0.w) << 16);
        val[2] = (uint_t)f2b(v1.x) | ((uint_t)f2b(v1.y) << 16);
        val[3] = (uint_t)f2b(v1.z) | ((uint_t)f2b(v1.w) << 16);
      }
      *(uint4v*)&As[row * 128 + ((c ^ (row & 7)) * 8)] = val;
    }
#pragma unroll
    for (int it = 0; it < 8; ++it) {
      int n = it * 16 + (tid >> 4);
      int c = tid & 15;
      uint4v val = {0, 0, 0, 0};
      int gk = k0 + c * 8;
      if (gk < K)
        val = *(const uint4v*)(WT + (size_t)n * K + gk);
      *(uint4v*)&Ws[n * 128 + ((c ^ (n & 7)) * 8)] = val;
    }
    __syncthreads();
#pragma unroll
    for (int ks = 0; ks < 4; ++ks) {
      int chunk = ks * 4 + lg;
      bf16x8 af[2], bfr[8];
#pragma unroll
      for (int mt = 0; mt < 2; ++mt) {
        int row = wave * 32 + mt * 16 + lr;
        af[mt] = *(const bf16x8*)&As[row * 128 + ((chunk ^ (row & 7)) * 8)];
      }
#pragma unroll
      for (int nt = 0; nt < 8; ++nt) {
        int n = nt * 16 + lr;
        bfr[nt] = *(const bf16x8*)&Ws[n * 128 + ((chunk ^ (n & 7)) * 8)];
      }
#pragma unroll
      for (int mt = 0; mt < 2; ++mt)
#pragma unroll
        for (int nt = 0; nt < 8; ++nt)
          acc[mt][nt] = __builtin_amdgcn_mfma_f32_16x16x32_bf16(
              af[mt], bfr[nt], acc[mt][nt], 0, 0, 0);
    }
    __syncthreads();
  }

  float bv[8];
#pragma unroll
  for (int nt = 0; nt < 8; ++nt) bv[nt] = bias[nt * 16 + lr];

#pragma unroll
  for (int mt = 0; mt < 2; ++mt) {
    int rbase = bm + wave * 32 + mt * 16 + lg * 4;
#pragma unroll
    for (int i = 0; i < 4; ++i) {
      int row = rbase + i;
      if (row >= M) continue;
#pragma unroll
      for (int nt = 0; nt < 8; ++nt)
        Cout[(size_t)row * 128 + nt * 16 + lr] = f2b(acc[mt][nt][i] + bv[nt]);
    }
  }
}

// ---------------- fused aggregate + per-relation GEMM; C rows scattered to dst-major via perm ----------------
__global__ __launch_bounds__(256, 2) void gemm_rel_agg(
    const ushort_t* __restrict__ xb, const int* __restrict__ segrow,
    const int* __restrict__ sorted_src, const int* __restrict__ rowstart,
    const int* __restrict__ perm,
    const ushort_t* __restrict__ WT_all, ushort_t* __restrict__ tC) {
  __shared__ ushort_t As[128 * 128];
  __shared__ ushort_t Ws[128 * 128];
  const int rel = blockIdx.y;
  const int start = rowstart[rel], end = rowstart[rel + 1];
  const int bm = start + blockIdx.x * 128;
  if (bm >= end) return;
  const ushort_t* WT = WT_all + (size_t)rel * 16384;
  const int tid = threadIdx.x;
  const int wave = tid >> 6, lane = tid & 63;
  const int lr = lane & 15, lg = lane >> 4;

  // stage A: per-pair mean gathered from xb
#pragma unroll
  for (int it = 0; it < 8; ++it) {
    int row16 = it * 16 + (tid >> 4);
    int sl = tid & 15;
    int g = bm + row16;
    uint4v o = {0, 0, 0, 0};
    if (g < end) {
      int s0 = segrow[g], s1 = segrow[g + 1];
      float a[8];
#pragma unroll
      for (int j = 0; j < 8; ++j) a[j] = 0.f;
      for (int i = s0; i < s1; ++i) {
        int s = sorted_src[i];
        uint4v v = *(const uint4v*)(xb + (size_t)s * DD + sl * 8);
#pragma unroll
        for (int j = 0; j < 4; ++j) {
          a[j * 2]     += b2f((ushort_t)(v[j] & 0xffff));
          a[j * 2 + 1] += b2f((ushort_t)(v[j] >> 16));
        }
      }
      float sc = 1.0f / (float)(s1 - s0);
#pragma unroll
      for (int j = 0; j < 4; ++j)
        o[j] = (uint_t)f2b(a[j * 2] * sc) | ((uint_t)f2b(a[j * 2 + 1] * sc) << 16);
    }
    *(uint4v*)&As[row16 * 128 + ((sl ^ (row16 & 7)) * 8)] = o;
  }
#pragma unroll
  for (int it = 0; it < 8; ++it) {
    int n = it * 16 + (tid >> 4);
    int cc = tid & 15;
    uint4v val = *(const uint4v*)(WT + (size_t)n * 128 + cc * 8);
    *(uint4v*)&Ws[n * 128 + ((cc ^ (n & 7)) * 8)] = val;
  }
  __syncthreads();

  f32x4 acc[2][8];
#pragma unroll
  for (int mt = 0; mt < 2; ++mt)
#pragma unroll
    for (int nt = 0; nt < 8; ++nt) acc[mt][nt] = {0.f, 0.f, 0.f, 0.f};

#pragma unroll
  for (int ks = 0; ks < 4; ++ks) {
    int chunk = ks * 4 + lg;
    bf16x8 af[2], bfr[8];
#pragma unroll
    for (int mt = 0; mt < 2; ++mt) {
      int row = wave * 32 + mt * 16 + lr;
      af[mt] = *(const bf16x8*)&As[row * 128 + ((chunk ^ (row & 7)) * 8)];
    }
#pragma unroll
    for (int nt = 0; nt < 8; ++nt) {
      int n = nt * 16 + lr;
      bfr[nt] = *(const bf16x8*)&Ws[n * 128 + ((chunk ^ (n & 7)) * 8)];
    }
#pragma unroll
    for (int mt = 0; mt < 2; ++mt)
#pragma unroll
      for (int nt = 0; nt < 8; ++nt)
        acc[mt][nt] = __builtin_amdgcn_mfma_f32_16x16x32_bf16(
            af[mt], bfr[nt], acc[mt][nt], 0, 0, 0);
  }

#pragma unroll
  for (int mt = 0; mt < 2; ++mt) {
    int rbase = bm + wave * 32 + mt * 16 + lg * 4;
#pragma unroll
    for (int i = 0; i < 4; ++i) {
      int row = rbase + i;
      if (row >= end) continue;
      int prow = perm[row];
#pragma unroll
      for (int nt = 0; nt < 8; ++nt)
        tC[(size_t)prow * 128 + nt * 16 + lr] = f2b(acc[mt][nt][i]);
    }
  }
}

// ---------------- fused root GEMM + dst-major streaming combine ----------------
// C = xb@rootT + bias + sum over tC rows [dstrow[d], dstrow[d+1]); RELU_BF: relu+bf16 -> xbout
// (in-place ok), else f32 -> fout. Grid must be exactly NN/128 blocks.
template <bool RELU_BF>
__global__ __launch_bounds__(256, 2) void gemm_root_combine(
    const ushort_t* __restrict__ Axb, const ushort_t* __restrict__ WT,
    const float* __restrict__ bias, const int* __restrict__ dstrow,
    const ushort_t* __restrict__ tC, float* __restrict__ fout,
    ushort_t* __restrict__ xbout) {
  __shared__ ushort_t smem[2 * 128 * 128];   // 64 KB: As|Ws, reused as f32 Cs
  ushort_t* As = smem;
  ushort_t* Ws = smem + 128 * 128;
  const int tid = threadIdx.x;
  const int bm = blockIdx.x * 128;
  const int wave = tid >> 6, lane = tid & 63;
  const int lr = lane & 15, lg = lane >> 4;

#pragma unroll
  for (int it = 0; it < 8; ++it) {
    int row = it * 16 + (tid >> 4);
    int c = tid & 15;
    uint4v val = *(const uint4v*)(Axb + (size_t)(bm + row) * 128 + c * 8);
    *(uint4v*)&As[row * 128 + ((c ^ (row & 7)) * 8)] = val;
  }
#pragma unroll
  for (int it = 0; it < 8; ++it) {
    int n = it * 16 + (tid >> 4);
    int c = tid & 15;
    uint4v val = *(const uint4v*)(WT + (size_t)n * 128 + c * 8);
    *(uint4v*)&Ws[n * 128 + ((c ^ (n & 7)) * 8)] = val;
  }
  __syncthreads();

  f32x4 acc[2][8];
#pragma unroll
  for (int mt = 0; mt < 2; ++mt)
#pragma unroll
    for (int nt = 0; nt < 8; ++nt) acc[mt][nt] = {0.f, 0.f, 0.f, 0.f};

#pragma unroll
  for (int ks = 0; ks < 4; ++ks) {
    int chunk = ks * 4 + lg;
    bf16x8 af[2], bfr[8];
#pragma unroll
    for (int mt = 0; mt < 2; ++mt) {
      int row = wave * 32 + mt * 16 + lr;
      af[mt] = *(const bf16x8*)&As[row * 128 + ((chunk ^ (row & 7)) * 8)];
    }
#pragma unroll
    for (int nt = 0; nt < 8; ++nt) {
      int n = nt * 16 + lr;
      bfr[nt] = *(const bf16x8*)&Ws[n * 128 + ((chunk ^ (n & 7)) * 8)];
    }
#pragma unroll
    for (int mt = 0; mt < 2; ++mt)
#pragma unroll
      for (int nt = 0; nt < 8; ++nt)
        acc[mt][nt] = __builtin_amdgcn_mfma_f32_16x16x32_bf16(
            af[mt], bfr[nt], acc[mt][nt], 0, 0, 0);
  }
  __syncthreads();   // done reading As/Ws

  // park C (+bias) in LDS as f32, bank-swizzled: col' = col ^ (lg*8)
  float* Cs = (float*)smem;
  float bv[8];
#pragma unroll
  for (int nt = 0; nt < 8; ++nt) bv[nt] = bias[nt * 16 + lr];
#pragma unroll
  for (int mt = 0; mt < 2; ++mt) {
    int rl = wave * 32 + mt * 16 + lg * 4;
#pragma unroll
    for (int i = 0; i < 4; ++i)
#pragma unroll
      for (int nt = 0; nt < 8; ++nt)
        Cs[(rl + i) * 128 + ((nt * 16 + lr) ^ (lg * 8))] = acc[mt][nt][i] + bv[nt];
  }
  __syncthreads();

  const uint_t* tCu = (const uint_t*)tC;

  // combine: each wave owns 32 dst rows; tC rows for a dst are contiguous (dst-major)
  for (int rr = 0; rr < 32; ++rr) {
    int rl = wave * 32 + rr;
    int dstn = bm + rl;
    int ps0 = dstrow[dstn], ps1 = dstrow[dstn + 1];
    int k = ps1 - ps0;
    // un-swizzle Cs read: logical cols (2*lane, 2*lane+1)
    int swzh = ((rr >> 2) & 3) * 4;
    float2 v = ((const float2*)(Cs + (size_t)rl * 128))[lane ^ swzh];
    uint_t tv[8];
#pragma unroll
    for (int j = 0; j < 8; ++j) {
      int idx = ps0 + ((j < k) ? j : 0);
      tv[j] = tCu[(size_t)idx * 64 + lane];
    }
#pragma unroll
    for (int j = 0; j < 8; ++j) {
      uint_t t = (j < k) ? tv[j] : 0u;
      v.x += b2f((ushort_t)(t & 0xffff));
      v.y += b2f((ushort_t)(t >> 16));
    }
    if (RELU_BF) {
      uint_t o = (uint_t)f2b(fmaxf(v.x, 0.f)) | ((uint_t)f2b(fmaxf(v.y, 0.f)) << 16);
      ((uint_t*)(xbout + (size_t)dstn * 128))[lane] = o;
    } else {
      ((float2*)(fout + (size_t)dstn * 128))[lane] = v;
    }
  }
}

// ---------------- edge bucketing ----------------
__global__ void count_kernel(const int* __restrict__ dstv, const int* __restrict__ et,
                             int* __restrict__ cnt, int E) {
  int e = blockIdx.x * blockDim.x + threadIdx.x;
  if (e < E) atomicAdd(&cnt[(size_t)et[e] * NN + dstv[e]], 1);
}

// dual scan: outA = exscan(in), outB = exscan(in>0)
__global__ __launch_bounds__(256) void scan1_dual(const int* __restrict__ in,
                                                  int* __restrict__ outA, int* __restrict__ outB,
                                                  int* __restrict__ pA, int* __restrict__ pB, int n) {
  __shared__ int sumsA[256], sumsB[256];
  int tid = threadIdx.x;
  int base = blockIdx.x * 2048 + tid * 8;
  int vA[8], vB[8];
  int sA = 0, sB = 0;
#pragma unroll
  for (int i = 0; i < 8; ++i) {
    int idx = base + i;
    int x = (idx < n) ? in[idx] : 0;
    vA[i] = sA; vB[i] = sB;
    sA += x; sB += (x > 0) ? 1 : 0;
  }
  sumsA[tid] = sA; sumsB[tid] = sB;
  __syncthreads();
  for (int off = 1; off < 256; off <<= 1) {
    int tA = (tid >= off) ? sumsA[tid - off] : 0;
    int tB = (tid >= off) ? sumsB[tid - off] : 0;
    __syncthreads();
    sumsA[tid] += tA; sumsB[tid] += tB;
    __syncthreads();
  }
  int exA = (tid == 0) ? 0 : sumsA[tid - 1];
  int exB = (tid == 0) ? 0 : sumsB[tid - 1];
  if (tid == 255) { pA[blockIdx.x] = sumsA[255]; pB[blockIdx.x] = sumsB[255]; }
#pragma unroll
  for (int i = 0; i < 8; ++i) {
    int idx = base + i;
    if (idx < n) { outA[idx] = exA + vA[i]; outB[idx] = exB + vB[i]; }
  }
}

__global__ __launch_bounds__(256) void scan2_kernel(int* __restrict__ partials, int nb) {
  __shared__ int sums[256];
  int tid = threadIdx.x;
  int per = (nb + 255) / 256;
  int start = tid * per;
  int s = 0;
  for (int i = 0; i < per; ++i) {
    int idx = start + i;
    if (idx < nb) s += partials[idx];
  }
  sums[tid] = s;
  __syncthreads();
  for (int off = 1; off < 256; off <<= 1) {
    int t = (tid >= off) ? sums[tid - off] : 0;
    __syncthreads();
    sums[tid] += t;
    __syncthreads();
  }
  int excl = (tid == 0) ? 0 : sums[tid - 1];
  for (int i = 0; i < per; ++i) {
    int idx = start + i;
    if (idx < nb) {
      int t = partials[idx];
      partials[idx] = excl;
      excl += t;
    }
  }
}

__global__ void scan3_dual(int* __restrict__ outA, int* __restrict__ outB,
                           const int* __restrict__ pA, const int* __restrict__ pB, int n) {
  int base = blockIdx.x * 2048 + threadIdx.x * 8;
  int aA = pA[blockIdx.x], aB = pB[blockIdx.x];
#pragma unroll
  for (int i = 0; i < 8; ++i) {
    int idx = base + i;
    if (idx < n) { outA[idx] += aA; outB[idx] += aB; }
  }
}

// single scan (for dstrow over NN)
__global__ __launch_bounds__(256) void scan1_kernel(const int* __restrict__ in, int* __restrict__ out,
                                                    int* __restrict__ partials, int n) {
  __shared__ int sums[256];
  int tid = threadIdx.x;
  int base = blockIdx.x * 2048 + tid * 8;
  int v[8];
  int s = 0;
#pragma unroll
  for (int i = 0; i < 8; ++i) {
    int idx = base + i;
    int x = (idx < n) ? in[idx] : 0;
    v[i] = s;
    s += x;
  }
  sums[tid] = s;
  __syncthreads();
  for (int off = 1; off < 256; off <<= 1) {
    int t = (tid >= off) ? sums[tid - off] : 0;
    __syncthreads();
    sums[tid] += t;
    __syncthreads();
  }
  int excl = (tid == 0) ? 0 : sums[tid - 1];
  if (tid == 255) partials[blockIdx.x] = sums[255];
#pragma unroll
  for (int i = 0; i < 8; ++i) {
    int idx = base + i;
    if (idx < n) out[idx] = excl + v[i];
  }
}

__global__ void scan3_kernel(int* __restrict__ out, const int* __restrict__ partials, int n) {
  int base = blockIdx.x * 2048 + threadIdx.x * 8;
  int add = partials[blockIdx.x];
#pragma unroll
  for (int i = 0; i < 8; ++i) {
    int idx = base + i;
    if (idx < n) out[idx] += add;
  }
}

// active relation count per dst
__global__ void activecnt_kernel(const int* __restrict__ cnt, int* __restrict__ ac) {
  int d = blockIdx.x * blockDim.x + threadIdx.x;
  if (d >= NN) return;
  int s = 0;
#pragma unroll
  for (int r = 0; r < RR; ++r) s += (cnt[(size_t)r * NN + d] > 0) ? 1 : 0;
  ac[d] = s;
}

// sentinels + per-relation compact-row starts
__global__ void finalize_kernel(const int* __restrict__ cnt, int* __restrict__ seg_off,
                                const int* __restrict__ rowid, int* __restrict__ rowstart,
                                int* __restrict__ segrow, int* __restrict__ dstrow) {
  int t = threadIdx.x;
  if (t == 0) seg_off[NRR] = EE;
  if (t < 8) rowstart[t] = rowid[(size_t)t * NN];
  if (t == 8) {
    int total = rowid[NRR - 1] + (cnt[NRR - 1] > 0 ? 1 : 0);
    rowstart[8] = total;
    segrow[total] = EE;
    dstrow[NN] = total;
  }
}

// per-dst: fill segrow (edge-seg start per rel-major row) and perm (rel-major row -> dst-major row)
__global__ void build_kernel(const int* __restrict__ cnt, const int* __restrict__ rowid,
                             const int* __restrict__ seg_off, const int* __restrict__ dstrow,
                             int* __restrict__ segrow, int* __restrict__ perm) {
  int d = blockIdx.x * blockDim.x + threadIdx.x;
  if (d >= NN) return;
  int ds = dstrow[d];
  int rank = 0;
#pragma unroll
  for (int r = 0; r < RR; ++r) {
    size_t p = (size_t)r * NN + d;
    if (cnt[p] > 0) {
      int rw = rowid[p];
      segrow[rw] = seg_off[p];
      perm[rw] = ds + rank;
      ++rank;
    }
  }
}

__global__ void place_kernel(const int* __restrict__ srcv, const int* __restrict__ dstv,
                             const int* __restrict__ et, const int* __restrict__ seg_off,
                             int* __restrict__ cursor, int* __restrict__ sorted_src, int E) {
  int e = blockIdx.x * blockDim.x + threadIdx.x;
  if (e < E) {
    int p = et[e] * NN + dstv[e];
    int slot = seg_off[p] + atomicAdd(&cursor[p], 1);
    sorted_src[slot] = srcv[e];
  }
}

static inline void launch_proj(const float* A, const ushort_t* WT, const float* bias,
                               ushort_t* C, int M, int K, hipStream_t stream) {
  hipLaunchKernelGGL(gemm_proj, dim3((M + 127) / 128), dim3(256), 0, stream,
                     A, WT, bias, C, M, K);
}

extern "C" void kernel_launch(void* const* d_in, const int* in_sizes, int n_in,
                              void* d_out, int out_size, void* d_ws, size_t ws_size,
                              hipStream_t stream) {
  const float* x_user = (const float*)d_in[0];
  const float* x_food = (const float*)d_in[1];
  const float* x_ing  = (const float*)d_in[2];
  const float* x_cat  = (const float*)d_in[3];
  const float* x_hab  = (const float*)d_in[4];
  const int*   eidx   = (const int*)d_in[5];
  const int*   etype  = (const int*)d_in[6];
  const float* Wu = (const float*)d_in[7];
  const float* bu = (const float*)d_in[8];
  const float* Wf = (const float*)d_in[9];
  const float* bfp = (const float*)d_in[10];
  const float* Wi = (const float*)d_in[11];
  const float* bi = (const float*)d_in[12];
  const float* Wc = (const float*)d_in[13];
  const float* bc = (const float*)d_in[14];
  const float* Wh = (const float*)d_in[15];
  const float* bh = (const float*)d_in[16];
  const float* W1    = (const float*)d_in[17];
  const float* root1 = (const float*)d_in[18];
  const float* bias1 = (const float*)d_in[19];
  const float* W2    = (const float*)d_in[20];
  const float* root2 = (const float*)d_in[21];
  const float* bias2 = (const float*)d_in[22];

  const int* src = eidx;
  const int* dst = eidx + EE;

  // ---- workspace layout (~173 MB; transient bucketing arrays aliased inside tC) ----
  char* ws = (char*)d_ws;
  ushort_t* xb  = (ushort_t*)(ws);                       // 40,960,000 B
  ushort_t* tC  = (ushort_t*)(ws + 40960000);            // 124,416,000 B (CAP1 rows)
  // aliases inside tC (dead before any tC write):
  int* seg_off  = (int*)(ws + 40960000);                 // 5,120,064 B
  int* rowid    = (int*)(ws + 46080064);                 // 5,120,000 B
  int* cnt_i    = (int*)(ws + 51200064);                 // 5,120,000 B (also cursor)
  int* activec  = (int*)(ws + 56320064);                 // 640,000 B
  // persistent (outside tC):
  int* segrow   = (int*)(ws + 165376000);                // 1,944,064 B
  int* perm     = (int*)(ws + 167320064);                // 1,944,064 B
  int* dstrow   = (int*)(ws + 169264128);                // 640,064 B
  int* sorted_src = (int*)(ws + 169904192);              // 2,400,000 B
  int* rowstart   = (int*)(ws + 172304192);              // 64 B
  int* pA         = (int*)(ws + 172304256);              // 4,096 B
  int* pB         = (int*)(ws + 172308352);              // 4,096 B
  ushort_t* wbuf  = (ushort_t*)(ws + 172312448);         // 753,664 B  (end ~173.07 MB)

  ushort_t* WuT = wbuf;            // 128x256
  ushort_t* WfT = wbuf + 32768;    // 128x128
  ushort_t* WiT = wbuf + 49152;
  ushort_t* WcT = wbuf + 65536;    // 128x64
  ushort_t* WhT = wbuf + 73728;
  ushort_t* r1T = wbuf + 81920;    // 128x128
  ushort_t* r2T = wbuf + 98304;
  ushort_t* W1T = wbuf + 114688;   // 8 x 128x128
  ushort_t* W2T = wbuf + 245760;

  float* out = (float*)d_out;

  // ---- weight conversion + transpose (single kernel) ----
  WSrcs wsrc;
  wsrc.s[0] = Wu; wsrc.s[1] = Wf; wsrc.s[2] = Wi; wsrc.s[3] = Wc; wsrc.s[4] = Wh;
  wsrc.s[5] = root1; wsrc.s[6] = root2; wsrc.s[7] = W1; wsrc.s[8] = W2;
  hipLaunchKernelGGL(wconv_all_kernel, dim3((WTOT + 255) / 256), dim3(256), 0, stream,
                     wsrc, wbuf);

  // ---- input projections -> xb (bf16 x_all) ----
  launch_proj(x_user, WuT, bu, xb + (size_t)0 * DD,      50000, 256, stream);
  launch_proj(x_food, WfT, bfp, xb + (size_t)50000 * DD, 50000, 128, stream);
  launch_proj(x_ing,  WiT, bi, xb + (size_t)100000 * DD, 50000, 128, stream);
  launch_proj(x_cat,  WcT, bc, xb + (size_t)150000 * DD, 5000,  64,  stream);
  launch_proj(x_hab,  WhT, bh, xb + (size_t)155000 * DD, 5000,  64,  stream);

  // ---- bucket edges by (relation, dst); build segrow / perm / dstrow / rowstart ----
  hipMemsetAsync(cnt_i, 0, (size_t)NRR * 4, stream);
  hipLaunchKernelGGL(count_kernel, dim3((EE + 255) / 256), dim3(256), 0, stream,
                     dst, etype, cnt_i, EE);
  {
    int nb = (NRR + 2047) / 2048;
    hipLaunchKernelGGL(scan1_dual, dim3(nb), dim3(256), 0, stream,
                       cnt_i, seg_off, rowid, pA, pB, NRR);
    hipLaunchKernelGGL(scan2_kernel, dim3(1), dim3(256), 0, stream, pA, nb);
    hipLaunchKernelGGL(scan2_kernel, dim3(1), dim3(256), 0, stream, pB, nb);
    hipLaunchKernelGGL(scan3_dual, dim3(nb), dim3(256), 0, stream,
                       seg_off, rowid, pA, pB, NRR);
  }
  hipLaunchKernelGGL(activecnt_kernel, dim3((NN + 255) / 256), dim3(256), 0, stream,
                     cnt_i, activec);
  {
    int nb = (NN + 2047) / 2048;
    hipLaunchKernelGGL(scan1_kernel, dim3(nb), dim3(256), 0, stream, activec, dstrow, pA, NN);
    hipLaunchKernelGGL(scan2_kernel, dim3(1), dim3(256), 0, stream, pA, nb);
    hipLaunchKernelGGL(scan3_kernel, dim3(nb), dim3(256), 0, stream, dstrow, pA, NN);
  }
  hipLaunchKernelGGL(finalize_kernel, dim3(1), dim3(64), 0, stream,
                     cnt_i, seg_off, rowid, rowstart, segrow, dstrow);
  hipLaunchKernelGGL(build_kernel, dim3((NN + 255) / 256), dim3(256), 0, stream,
                     cnt_i, rowid, seg_off, dstrow, segrow, perm);
  hipMemsetAsync(cnt_i, 0, (size_t)NRR * 4, stream);  // reuse as cursor
  hipLaunchKernelGGL(place_kernel, dim3((EE + 255) / 256), dim3(256), 0, stream,
                     src, dst, etype, seg_off, cnt_i, sorted_src, EE);

  const dim3 relGrid(512, RR);
  const dim3 rootGrid(NN / 128);   // 1250, exact

  // ---- conv1: tC = mean@W1 (dst-major); xb = relu(xb@root1 + bias1 + combine) in place ----
  hipLaunchKernelGGL(gemm_rel_agg, relGrid, dim3(256), 0, stream,
                     xb, segrow, sorted_src, rowstart, perm, W1T, tC);
  hipLaunchKernelGGL((gemm_root_combine<true>), rootGrid, dim3(256), 0, stream,
                     xb, r1T, bias1, dstrow, tC, (float*)nullptr, xb);

  // ---- conv2: tC = mean@W2 (dst-major); d_out = xb@root2 + bias2 + combine (f32) ----
  hipLaunchKernelGGL(gemm_rel_agg, relGrid, dim3(256), 0, stream,
                     xb, segrow, sorted_src, rowstart, perm, W2T, tC);
  hipLaunchKernelGGL((gemm_root_combine<false>), rootGrid, dim3(256), 0, stream,
                     xb, r2T, bias2, dstrow, tC, out, (ushort_t*)nullptr);
}

// Round 7
// 471.357 us; speedup vs baseline: 1.5529x; 1.2231x over previous
//
#include <hip/hip_runtime.h>

typedef unsigned short ushort_t;
typedef unsigned int uint_t;
typedef __attribute__((ext_vector_type(8))) __bf16 bf16x8;
typedef __attribute__((ext_vector_type(4))) float f32x4;
typedef __attribute__((ext_vector_type(4))) uint_t uint4v;

#define NN 160000
#define DD 128
#define EE 600000
#define RR 8
#define NRR (NN * RR)          // 1,280,000 pairs
#define CAP1 486000            // compact-row cap (mean ~479.1K, +13 sigma)
#define WTOT 376832            // total bf16 weight elements

__device__ __forceinline__ ushort_t f2b(float f) {
  uint_t u = __float_as_uint(f);
  u = u + 0x7fffu + ((u >> 16) & 1u);   // round-nearest-even
  return (ushort_t)(u >> 16);
}
__device__ __forceinline__ float b2f(ushort_t u) {
  return __uint_as_float(((uint_t)u) << 16);
}

// ---------------- merged weight convert+transpose for all 9 matrices ----------------
struct WSrcs { const float* s[9]; };

__global__ void wconv_all_kernel(WSrcs srcs, ushort_t* __restrict__ wbuf) {
  int i = blockIdx.x * blockDim.x + threadIdx.x;
  if (i >= WTOT) return;
  int m, start, K;
  if      (i < 32768)  { m = 0; start = 0;      K = 256; }
  else if (i < 49152)  { m = 1; start = 32768;  K = 128; }
  else if (i < 65536)  { m = 2; start = 49152;  K = 128; }
  else if (i < 73728)  { m = 3; start = 65536;  K = 64;  }
  else if (i < 81920)  { m = 4; start = 73728;  K = 64;  }
  else if (i < 98304)  { m = 5; start = 81920;  K = 128; }
  else if (i < 114688) { m = 6; start = 98304;  K = 128; }
  else if (i < 245760) { m = 7; start = 114688; K = 128; }
  else                 { m = 8; start = 245760; K = 128; }
  int local = i - start;
  int per = K * 128;
  int mat = local / per, rem = local - mat * per;
  int k = rem >> 7, n = rem & 127;
  wbuf[start + mat * per + n * K + k] = f2b(srcs.s[m][local]);
}

// ---------------- projection GEMM: C[M x 128](bf16) = A[M x K](f32) @ WT[128 x K](bf16) ----------------
__global__ __launch_bounds__(256, 2) void gemm_proj(
    const float* __restrict__ Ain, const ushort_t* __restrict__ WT,
    const float* __restrict__ bias, ushort_t* __restrict__ Cout, int M, int K) {
  __shared__ ushort_t As[128 * 128];
  __shared__ ushort_t Ws[128 * 128];
  const int tid = threadIdx.x;
  const int bm = blockIdx.x * 128;
  const int wave = tid >> 6, lane = tid & 63;
  const int lr = lane & 15;
  const int lg = lane >> 4;

  f32x4 acc[2][8];
#pragma unroll
  for (int mt = 0; mt < 2; ++mt)
#pragma unroll
    for (int nt = 0; nt < 8; ++nt) acc[mt][nt] = {0.f, 0.f, 0.f, 0.f};

  for (int k0 = 0; k0 < K; k0 += 128) {
#pragma unroll
    for (int it = 0; it < 8; ++it) {
      int row = it * 16 + (tid >> 4);
      int c = tid & 15;
      uint4v val = {0, 0, 0, 0};
      int grow = bm + row, gk = k0 + c * 8;
      if (grow < M && gk < K) {
        const float* ap = Ain + (size_t)grow * K + gk;
        float4 v0 = *(const float4*)ap;
        float4 v1 = *(const float4*)(ap + 4);
        val[0] = (uint_t)f2b(v0.x) | ((uint_t)f2b(v0.y) << 16);
        val[1] = (uint_t)f2b(v0.z) | ((uint_t)f2b(v0.w) << 16);
        val[2] = (uint_t)f2b(v1.x) | ((uint_t)f2b(v1.y) << 16);
        val[3] = (uint_t)f2b(v1.z) | ((uint_t)f2b(v1.w) << 16);
      }
      *(uint4v*)&As[row * 128 + ((c ^ (row & 7)) * 8)] = val;
    }
#pragma unroll
    for (int it = 0; it < 8; ++it) {
      int n = it * 16 + (tid >> 4);
      int c = tid & 15;
      uint4v val = {0, 0, 0, 0};
      int gk = k0 + c * 8;
      if (gk < K)
        val = *(const uint4v*)(WT + (size_t)n * K + gk);
      *(uint4v*)&Ws[n * 128 + ((c ^ (n & 7)) * 8)] = val;
    }
    __syncthreads();
#pragma unroll
    for (int ks = 0; ks < 4; ++ks) {
      int chunk = ks * 4 + lg;
      bf16x8 af[2], bfr[8];
#pragma unroll
      for (int mt = 0; mt < 2; ++mt) {
        int row = wave * 32 + mt * 16 + lr;
        af[mt] = *(const bf16x8*)&As[row * 128 + ((chunk ^ (row & 7)) * 8)];
      }
#pragma unroll
      for (int nt = 0; nt < 8; ++nt) {
        int n = nt * 16 + lr;
        bfr[nt] = *(const bf16x8*)&Ws[n * 128 + ((chunk ^ (n & 7)) * 8)];
      }
#pragma unroll
      for (int mt = 0; mt < 2; ++mt)
#pragma unroll
        for (int nt = 0; nt < 8; ++nt)
          acc[mt][nt] = __builtin_amdgcn_mfma_f32_16x16x32_bf16(
              af[mt], bfr[nt], acc[mt][nt], 0, 0, 0);
    }
    __syncthreads();
  }

  float bv[8];
#pragma unroll
  for (int nt = 0; nt < 8; ++nt) bv[nt] = bias[nt * 16 + lr];

#pragma unroll
  for (int mt = 0; mt < 2; ++mt) {
    int rbase = bm + wave * 32 + mt * 16 + lg * 4;
#pragma unroll
    for (int i = 0; i < 4; ++i) {
      int row = rbase + i;
      if (row >= M) continue;
#pragma unroll
      for (int nt = 0; nt < 8; ++nt)
        Cout[(size_t)row * 128 + nt * 16 + lr] = f2b(acc[mt][nt][i] + bv[nt]);
    }
  }
}

// ---------------- fused aggregate + per-relation GEMM (BM=64, MLP-batched gather) ----------------
// A-tile rows are (rel,dst) pair means gathered from xb; C rows scattered dst-major via perm.
__global__ __launch_bounds__(256, 3) void gemm_rel_agg(
    const ushort_t* __restrict__ xb, const int* __restrict__ segrow,
    const int* __restrict__ sorted_src, const int* __restrict__ rowstart,
    const int* __restrict__ perm,
    const ushort_t* __restrict__ WT_all, ushort_t* __restrict__ tC) {
  __shared__ ushort_t As[64 * 128];    // 16 KB
  __shared__ ushort_t Ws[128 * 128];   // 32 KB
  const int rel = blockIdx.y;
  const int start = rowstart[rel], end = rowstart[rel + 1];
  const int bm = start + blockIdx.x * 64;
  if (bm >= end) return;
  const ushort_t* WT = WT_all + (size_t)rel * 16384;
  const int tid = threadIdx.x;
  const int wave = tid >> 6, lane = tid & 63;
  const int lr = lane & 15, lg = lane >> 4;
  const int grp = tid >> 4;    // 0..15
  const int sl = tid & 15;

  // batched gather: group handles rows q*16+grp, q=0..3; bounds/first-src/first-row
  // issued as three independent load batches (MLP), then per-row finish.
  int gs[4], ge[4];
#pragma unroll
  for (int q = 0; q < 4; ++q) {
    int g = bm + q * 16 + grp;
    bool v = g < end;
    gs[q] = v ? segrow[g] : 0;
    ge[q] = v ? segrow[g + 1] : 0;
  }
  int fs[4];
#pragma unroll
  for (int q = 0; q < 4; ++q)
    fs[q] = (ge[q] > gs[q]) ? sorted_src[gs[q]] : 0;
  uint4v fv[4];
#pragma unroll
  for (int q = 0; q < 4; ++q)
    fv[q] = *(const uint4v*)(xb + (size_t)fs[q] * DD + sl * 8);

#pragma unroll
  for (int q = 0; q < 4; ++q) {
    int row = q * 16 + grp;
    int cnt = ge[q] - gs[q];
    uint4v o = {0, 0, 0, 0};
    if (cnt == 1) {
      o = fv[q];                     // mean of one = itself (bit-exact copy)
    } else if (cnt > 1) {
      float a[8];
#pragma unroll
      for (int j = 0; j < 4; ++j) {
        a[j * 2]     = b2f((ushort_t)(fv[q][j] & 0xffff));
        a[j * 2 + 1] = b2f((ushort_t)(fv[q][j] >> 16));
      }
      for (int i = gs[q] + 1; i < ge[q]; ++i) {
        int s = sorted_src[i];
        uint4v v2 = *(const uint4v*)(xb + (size_t)s * DD + sl * 8);
#pragma unroll
        for (int j = 0; j < 4; ++j) {
          a[j * 2]     += b2f((ushort_t)(v2[j] & 0xffff));
          a[j * 2 + 1] += b2f((ushort_t)(v2[j] >> 16));
        }
      }
      float sc = 1.0f / (float)cnt;
#pragma unroll
      for (int j = 0; j < 4; ++j)
        o[j] = (uint_t)f2b(a[j * 2] * sc) | ((uint_t)f2b(a[j * 2 + 1] * sc) << 16);
    }
    *(uint4v*)&As[row * 128 + ((sl ^ (row & 7)) * 8)] = o;
  }
#pragma unroll
  for (int it = 0; it < 8; ++it) {
    int n = it * 16 + grp;
    uint4v val = *(const uint4v*)(WT + (size_t)n * 128 + sl * 8);
    *(uint4v*)&Ws[n * 128 + ((sl ^ (n & 7)) * 8)] = val;
  }
  __syncthreads();

  f32x4 acc[8];
#pragma unroll
  for (int nt = 0; nt < 8; ++nt) acc[nt] = {0.f, 0.f, 0.f, 0.f};

#pragma unroll
  for (int ks = 0; ks < 4; ++ks) {
    int chunk = ks * 4 + lg;
    int arow = wave * 16 + lr;
    bf16x8 af = *(const bf16x8*)&As[arow * 128 + ((chunk ^ (arow & 7)) * 8)];
    bf16x8 bfr[8];
#pragma unroll
    for (int nt = 0; nt < 8; ++nt) {
      int n = nt * 16 + lr;
      bfr[nt] = *(const bf16x8*)&Ws[n * 128 + ((chunk ^ (n & 7)) * 8)];
    }
#pragma unroll
    for (int nt = 0; nt < 8; ++nt)
      acc[nt] = __builtin_amdgcn_mfma_f32_16x16x32_bf16(af, bfr[nt], acc[nt], 0, 0, 0);
  }

  int rbase = bm + wave * 16 + lg * 4;
#pragma unroll
  for (int i = 0; i < 4; ++i) {
    int row = rbase + i;
    if (row >= end) continue;
    int prow = perm[row];
#pragma unroll
    for (int nt = 0; nt < 8; ++nt)
      tC[(size_t)prow * 128 + nt * 16 + lr] = f2b(acc[nt][i]);
  }
}

// ---------------- fused root GEMM + dst-major streaming combine (BM=64) ----------------
template <bool RELU_BF>
__global__ __launch_bounds__(256, 3) void gemm_root_combine(
    const ushort_t* __restrict__ Axb, const ushort_t* __restrict__ WT,
    const float* __restrict__ bias, const int* __restrict__ dstrow,
    const ushort_t* __restrict__ tC, float* __restrict__ fout,
    ushort_t* __restrict__ xbout) {
  __shared__ ushort_t smem[24576];     // 48 KB: As(16K) | Ws(32K); reused as f32 Cs(32K)
  ushort_t* As = smem;                 // [64*128]
  ushort_t* Ws = smem + 64 * 128;      // [128*128]
  const int tid = threadIdx.x;
  const int bm = blockIdx.x * 64;
  const int wave = tid >> 6, lane = tid & 63;
  const int lr = lane & 15, lg = lane >> 4;
  const int grp = tid >> 4, sl = tid & 15;

#pragma unroll
  for (int it = 0; it < 4; ++it) {
    int row = it * 16 + grp;
    uint4v val = *(const uint4v*)(Axb + (size_t)(bm + row) * 128 + sl * 8);
    *(uint4v*)&As[row * 128 + ((sl ^ (row & 7)) * 8)] = val;
  }
#pragma unroll
  for (int it = 0; it < 8; ++it) {
    int n = it * 16 + grp;
    uint4v val = *(const uint4v*)(WT + (size_t)n * 128 + sl * 8);
    *(uint4v*)&Ws[n * 128 + ((sl ^ (n & 7)) * 8)] = val;
  }
  // prefetch dstrow bounds for this wave's 16 rows (lane-parallel, one load)
  int wbase = bm + wave * 16;
  int bnd = (lane <= 16) ? dstrow[wbase + lane] : 0;
  __syncthreads();

  f32x4 acc[8];
#pragma unroll
  for (int nt = 0; nt < 8; ++nt) acc[nt] = {0.f, 0.f, 0.f, 0.f};

#pragma unroll
  for (int ks = 0; ks < 4; ++ks) {
    int chunk = ks * 4 + lg;
    int arow = wave * 16 + lr;
    bf16x8 af = *(const bf16x8*)&As[arow * 128 + ((chunk ^ (arow & 7)) * 8)];
    bf16x8 bfr[8];
#pragma unroll
    for (int nt = 0; nt < 8; ++nt) {
      int n = nt * 16 + lr;
      bfr[nt] = *(const bf16x8*)&Ws[n * 128 + ((chunk ^ (n & 7)) * 8)];
    }
#pragma unroll
    for (int nt = 0; nt < 8; ++nt)
      acc[nt] = __builtin_amdgcn_mfma_f32_16x16x32_bf16(af, bfr[nt], acc[nt], 0, 0, 0);
  }
  __syncthreads();   // done reading As/Ws

  // park C (+bias) in LDS as f32, bank-swizzled: col' = col ^ (lg*8)
  float* Cs = (float*)smem;
  float bv[8];
#pragma unroll
  for (int nt = 0; nt < 8; ++nt) bv[nt] = bias[nt * 16 + lr];
  {
    int rl0 = wave * 16 + lg * 4;
#pragma unroll
    for (int i = 0; i < 4; ++i)
#pragma unroll
      for (int nt = 0; nt < 8; ++nt)
        Cs[(rl0 + i) * 128 + ((nt * 16 + lr) ^ (lg * 8))] = acc[nt][i] + bv[nt];
  }
  __syncthreads();

  const uint_t* tCu = (const uint_t*)tC;

  // combine: each wave owns 16 dst rows; tC rows for a dst are contiguous (dst-major)
  for (int rr = 0; rr < 16; ++rr) {
    int rl = wave * 16 + rr;
    int dstn = bm + rl;
    int ps0 = __shfl(bnd, rr), ps1 = __shfl(bnd, rr + 1);
    int k = ps1 - ps0;
    int swzh = ((rr >> 2) & 3) * 4;
    float2 v = ((const float2*)(Cs + (size_t)rl * 128))[lane ^ swzh];
    uint_t tv[8];
#pragma unroll
    for (int j = 0; j < 8; ++j) {
      int idx = ps0 + ((j < k) ? j : 0);
      tv[j] = tCu[(size_t)idx * 64 + lane];
    }
#pragma unroll
    for (int j = 0; j < 8; ++j) {
      uint_t t = (j < k) ? tv[j] : 0u;
      v.x += b2f((ushort_t)(t & 0xffff));
      v.y += b2f((ushort_t)(t >> 16));
    }
    if (RELU_BF) {
      uint_t o = (uint_t)f2b(fmaxf(v.x, 0.f)) | ((uint_t)f2b(fmaxf(v.y, 0.f)) << 16);
      ((uint_t*)(xbout + (size_t)dstn * 128))[lane] = o;
    } else {
      ((float2*)(fout + (size_t)dstn * 128))[lane] = v;
    }
  }
}

// ---------------- edge bucketing ----------------
__global__ void count_kernel(const int* __restrict__ dstv, const int* __restrict__ et,
                             int* __restrict__ cnt, int E) {
  int e = blockIdx.x * blockDim.x + threadIdx.x;
  if (e < E) atomicAdd(&cnt[(size_t)et[e] * NN + dstv[e]], 1);
}

// dual scan: outA = exscan(in), outB = exscan(in>0)
__global__ __launch_bounds__(256) void scan1_dual(const int* __restrict__ in,
                                                  int* __restrict__ outA, int* __restrict__ outB,
                                                  int* __restrict__ pA, int* __restrict__ pB, int n) {
  __shared__ int sumsA[256], sumsB[256];
  int tid = threadIdx.x;
  int base = blockIdx.x * 2048 + tid * 8;
  int vA[8], vB[8];
  int sA = 0, sB = 0;
#pragma unroll
  for (int i = 0; i < 8; ++i) {
    int idx = base + i;
    int x = (idx < n) ? in[idx] : 0;
    vA[i] = sA; vB[i] = sB;
    sA += x; sB += (x > 0) ? 1 : 0;
  }
  sumsA[tid] = sA; sumsB[tid] = sB;
  __syncthreads();
  for (int off = 1; off < 256; off <<= 1) {
    int tA = (tid >= off) ? sumsA[tid - off] : 0;
    int tB = (tid >= off) ? sumsB[tid - off] : 0;
    __syncthreads();
    sumsA[tid] += tA; sumsB[tid] += tB;
    __syncthreads();
  }
  int exA = (tid == 0) ? 0 : sumsA[tid - 1];
  int exB = (tid == 0) ? 0 : sumsB[tid - 1];
  if (tid == 255) { pA[blockIdx.x] = sumsA[255]; pB[blockIdx.x] = sumsB[255]; }
#pragma unroll
  for (int i = 0; i < 8; ++i) {
    int idx = base + i;
    if (idx < n) { outA[idx] = exA + vA[i]; outB[idx] = exB + vB[i]; }
  }
}

__global__ __launch_bounds__(256) void scan2_two(int* __restrict__ pA, int* __restrict__ pB, int nb) {
  __shared__ int sums[256];
  int* partials = blockIdx.x ? pB : pA;
  int tid = threadIdx.x;
  int per = (nb + 255) / 256;
  int start = tid * per;
  int s = 0;
  for (int i = 0; i < per; ++i) {
    int idx = start + i;
    if (idx < nb) s += partials[idx];
  }
  sums[tid] = s;
  __syncthreads();
  for (int off = 1; off < 256; off <<= 1) {
    int t = (tid >= off) ? sums[tid - off] : 0;
    __syncthreads();
    sums[tid] += t;
    __syncthreads();
  }
  int excl = (tid == 0) ? 0 : sums[tid - 1];
  for (int i = 0; i < per; ++i) {
    int idx = start + i;
    if (idx < nb) {
      int t = partials[idx];
      partials[idx] = excl;
      excl += t;
    }
  }
}

__global__ void scan3_dual(int* __restrict__ outA, int* __restrict__ outB,
                           const int* __restrict__ pA, const int* __restrict__ pB, int n) {
  int base = blockIdx.x * 2048 + threadIdx.x * 8;
  int aA = pA[blockIdx.x], aB = pB[blockIdx.x];
#pragma unroll
  for (int i = 0; i < 8; ++i) {
    int idx = base + i;
    if (idx < n) { outA[idx] += aA; outB[idx] += aB; }
  }
}

// single scan (for dstrow over NN)
__global__ __launch_bounds__(256) void scan1_kernel(const int* __restrict__ in, int* __restrict__ out,
                                                    int* __restrict__ partials, int n) {
  __shared__ int sums[256];
  int tid = threadIdx.x;
  int base = blockIdx.x * 2048 + tid * 8;
  int v[8];
  int s = 0;
#pragma unroll
  for (int i = 0; i < 8; ++i) {
    int idx = base + i;
    int x = (idx < n) ? in[idx] : 0;
    v[i] = s;
    s += x;
  }
  sums[tid] = s;
  __syncthreads();
  for (int off = 1; off < 256; off <<= 1) {
    int t = (tid >= off) ? sums[tid - off] : 0;
    __syncthreads();
    sums[tid] += t;
    __syncthreads();
  }
  int excl = (tid == 0) ? 0 : sums[tid - 1];
  if (tid == 255) partials[blockIdx.x] = sums[255];
#pragma unroll
  for (int i = 0; i < 8; ++i) {
    int idx = base + i;
    if (idx < n) out[idx] = excl + v[i];
  }
}

__global__ __launch_bounds__(256) void scan2_kernel(int* __restrict__ partials, int nb) {
  __shared__ int sums[256];
  int tid = threadIdx.x;
  int per = (nb + 255) / 256;
  int start = tid * per;
  int s = 0;
  for (int i = 0; i < per; ++i) {
    int idx = start + i;
    if (idx < nb) s += partials[idx];
  }
  sums[tid] = s;
  __syncthreads();
  for (int off = 1; off < 256; off <<= 1) {
    int t = (tid >= off) ? sums[tid - off] : 0;
    __syncthreads();
    sums[tid] += t;
    __syncthreads();
  }
  int excl = (tid == 0) ? 0 : sums[tid - 1];
  for (int i = 0; i < per; ++i) {
    int idx = start + i;
    if (idx < nb) {
      int t = partials[idx];
      partials[idx] = excl;
      excl += t;
    }
  }
}

__global__ void scan3_kernel(int* __restrict__ out, const int* __restrict__ partials, int n) {
  int base = blockIdx.x * 2048 + threadIdx.x * 8;
  int add = partials[blockIdx.x];
#pragma unroll
  for (int i = 0; i < 8; ++i) {
    int idx = base + i;
    if (idx < n) out[idx] += add;
  }
}

// active relation count per dst
__global__ void activecnt_kernel(const int* __restrict__ cnt, int* __restrict__ ac) {
  int d = blockIdx.x * blockDim.x + threadIdx.x;
  if (d >= NN) return;
  int s = 0;
#pragma unroll
  for (int r = 0; r < RR; ++r) s += (cnt[(size_t)r * NN + d] > 0) ? 1 : 0;
  ac[d] = s;
}

// sentinels + per-relation compact-row starts
__global__ void finalize_kernel(const int* __restrict__ cnt, int* __restrict__ seg_off,
                                const int* __restrict__ rowid, int* __restrict__ rowstart,
                                int* __restrict__ segrow, int* __restrict__ dstrow) {
  int t = threadIdx.x;
  if (t == 0) seg_off[NRR] = EE;
  if (t < 8) rowstart[t] = rowid[(size_t)t * NN];
  if (t == 8) {
    int total = rowid[NRR - 1] + (cnt[NRR - 1] > 0 ? 1 : 0);
    rowstart[8] = total;
    segrow[total] = EE;
    dstrow[NN] = total;
  }
}

// per-dst: fill segrow (edge-seg start per rel-major row) and perm (rel-major row -> dst-major row)
__global__ void build_kernel(const int* __restrict__ cnt, const int* __restrict__ rowid,
                             const int* __restrict__ seg_off, const int* __restrict__ dstrow,
                             int* __restrict__ segrow, int* __restrict__ perm) {
  int d = blockIdx.x * blockDim.x + threadIdx.x;
  if (d >= NN) return;
  int ds = dstrow[d];
  int rank = 0;
#pragma unroll
  for (int r = 0; r < RR; ++r) {
    size_t p = (size_t)r * NN + d;
    if (cnt[p] > 0) {
      int rw = rowid[p];
      segrow[rw] = seg_off[p];
      perm[rw] = ds + rank;
      ++rank;
    }
  }
}

__global__ void place_kernel(const int* __restrict__ srcv, const int* __restrict__ dstv,
                             const int* __restrict__ et, const int* __restrict__ seg_off,
                             int* __restrict__ cursor, int* __restrict__ sorted_src, int E) {
  int e = blockIdx.x * blockDim.x + threadIdx.x;
  if (e < E) {
    int p = et[e] * NN + dstv[e];
    int slot = seg_off[p] + atomicAdd(&cursor[p], 1);
    sorted_src[slot] = srcv[e];
  }
}

static inline void launch_proj(const float* A, const ushort_t* WT, const float* bias,
                               ushort_t* C, int M, int K, hipStream_t stream) {
  hipLaunchKernelGGL(gemm_proj, dim3((M + 127) / 128), dim3(256), 0, stream,
                     A, WT, bias, C, M, K);
}

extern "C" void kernel_launch(void* const* d_in, const int* in_sizes, int n_in,
                              void* d_out, int out_size, void* d_ws, size_t ws_size,
                              hipStream_t stream) {
  const float* x_user = (const float*)d_in[0];
  const float* x_food = (const float*)d_in[1];
  const float* x_ing  = (const float*)d_in[2];
  const float* x_cat  = (const float*)d_in[3];
  const float* x_hab  = (const float*)d_in[4];
  const int*   eidx   = (const int*)d_in[5];
  const int*   etype  = (const int*)d_in[6];
  const float* Wu = (const float*)d_in[7];
  const float* bu = (const float*)d_in[8];
  const float* Wf = (const float*)d_in[9];
  const float* bfp = (const float*)d_in[10];
  const float* Wi = (const float*)d_in[11];
  const float* bi = (const float*)d_in[12];
  const float* Wc = (const float*)d_in[13];
  const float* bc = (const float*)d_in[14];
  const float* Wh = (const float*)d_in[15];
  const float* bh = (const float*)d_in[16];
  const float* W1    = (const float*)d_in[17];
  const float* root1 = (const float*)d_in[18];
  const float* bias1 = (const float*)d_in[19];
  const float* W2    = (const float*)d_in[20];
  const float* root2 = (const float*)d_in[21];
  const float* bias2 = (const float*)d_in[22];

  const int* src = eidx;
  const int* dst = eidx + EE;

  // ---- workspace layout (~173 MB; transient bucketing arrays aliased inside tC) ----
  char* ws = (char*)d_ws;
  ushort_t* xb  = (ushort_t*)(ws);                       // 40,960,000 B
  ushort_t* tC  = (ushort_t*)(ws + 40960000);            // 124,416,000 B (CAP1 rows)
  // aliases inside tC (dead before any tC write):
  int* seg_off  = (int*)(ws + 40960000);                 // 5,120,064 B
  int* rowid    = (int*)(ws + 46080064);                 // 5,120,000 B
  int* cnt_i    = (int*)(ws + 51200064);                 // 5,120,000 B (also cursor)
  int* activec  = (int*)(ws + 56320064);                 // 640,000 B
  // persistent (outside tC):
  int* segrow   = (int*)(ws + 165376000);                // 1,944,064 B
  int* perm     = (int*)(ws + 167320064);                // 1,944,064 B
  int* dstrow   = (int*)(ws + 169264128);                // 640,064 B
  int* sorted_src = (int*)(ws + 169904192);              // 2,400,000 B
  int* rowstart   = (int*)(ws + 172304192);              // 64 B
  int* pA         = (int*)(ws + 172304256);              // 4,096 B
  int* pB         = (int*)(ws + 172308352);              // 4,096 B
  ushort_t* wbuf  = (ushort_t*)(ws + 172312448);         // 753,664 B  (end ~173.07 MB)

  ushort_t* WuT = wbuf;            // 128x256
  ushort_t* WfT = wbuf + 32768;    // 128x128
  ushort_t* WiT = wbuf + 49152;
  ushort_t* WcT = wbuf + 65536;    // 128x64
  ushort_t* WhT = wbuf + 73728;
  ushort_t* r1T = wbuf + 81920;    // 128x128
  ushort_t* r2T = wbuf + 98304;
  ushort_t* W1T = wbuf + 114688;   // 8 x 128x128
  ushort_t* W2T = wbuf + 245760;

  float* out = (float*)d_out;

  // ---- weight conversion + transpose (single kernel) ----
  WSrcs wsrc;
  wsrc.s[0] = Wu; wsrc.s[1] = Wf; wsrc.s[2] = Wi; wsrc.s[3] = Wc; wsrc.s[4] = Wh;
  wsrc.s[5] = root1; wsrc.s[6] = root2; wsrc.s[7] = W1; wsrc.s[8] = W2;
  hipLaunchKernelGGL(wconv_all_kernel, dim3((WTOT + 255) / 256), dim3(256), 0, stream,
                     wsrc, wbuf);

  // ---- input projections -> xb (bf16 x_all) ----
  launch_proj(x_user, WuT, bu, xb + (size_t)0 * DD,      50000, 256, stream);
  launch_proj(x_food, WfT, bfp, xb + (size_t)50000 * DD, 50000, 128, stream);
  launch_proj(x_ing,  WiT, bi, xb + (size_t)100000 * DD, 50000, 128, stream);
  launch_proj(x_cat,  WcT, bc, xb + (size_t)150000 * DD, 5000,  64,  stream);
  launch_proj(x_hab,  WhT, bh, xb + (size_t)155000 * DD, 5000,  64,  stream);

  // ---- bucket edges by (relation, dst); build segrow / perm / dstrow / rowstart ----
  hipMemsetAsync(cnt_i, 0, (size_t)NRR * 4, stream);
  hipLaunchKernelGGL(count_kernel, dim3((EE + 255) / 256), dim3(256), 0, stream,
                     dst, etype, cnt_i, EE);
  {
    int nb = (NRR + 2047) / 2048;
    hipLaunchKernelGGL(scan1_dual, dim3(nb), dim3(256), 0, stream,
                       cnt_i, seg_off, rowid, pA, pB, NRR);
    hipLaunchKernelGGL(scan2_two, dim3(2), dim3(256), 0, stream, pA, pB, nb);
    hipLaunchKernelGGL(scan3_dual, dim3(nb), dim3(256), 0, stream,
                       seg_off, rowid, pA, pB, NRR);
  }
  hipLaunchKernelGGL(activecnt_kernel, dim3((NN + 255) / 256), dim3(256), 0, stream,
                     cnt_i, activec);
  {
    int nb = (NN + 2047) / 2048;
    hipLaunchKernelGGL(scan1_kernel, dim3(nb), dim3(256), 0, stream, activec, dstrow, pA, NN);
    hipLaunchKernelGGL(scan2_kernel, dim3(1), dim3(256), 0, stream, pA, nb);
    hipLaunchKernelGGL(scan3_kernel, dim3(nb), dim3(256), 0, stream, dstrow, pA, NN);
  }
  hipLaunchKernelGGL(finalize_kernel, dim3(1), dim3(64), 0, stream,
                     cnt_i, seg_off, rowid, rowstart, segrow, dstrow);
  hipLaunchKernelGGL(build_kernel, dim3((NN + 255) / 256), dim3(256), 0, stream,
                     cnt_i, rowid, seg_off, dstrow, segrow, perm);
  hipMemsetAsync(cnt_i, 0, (size_t)NRR * 4, stream);  // reuse as cursor
  hipLaunchKernelGGL(place_kernel, dim3((EE + 255) / 256), dim3(256), 0, stream,
                     src, dst, etype, seg_off, cnt_i, sorted_src, EE);

  const dim3 relGrid(1024, RR);    // 64-row tiles; ~60.5K rows/rel max -> 946 used
  const dim3 rootGrid(NN / 64);    // 2500, exact

  // ---- conv1: tC = mean@W1 (dst-major); xb = relu(xb@root1 + bias1 + combine) in place ----
  hipLaunchKernelGGL(gemm_rel_agg, relGrid, dim3(256), 0, stream,
                     xb, segrow, sorted_src, rowstart, perm, W1T, tC);
  hipLaunchKernelGGL((gemm_root_combine<true>), rootGrid, dim3(256), 0, stream,
                     xb, r1T, bias1, dstrow, tC, (float*)nullptr, xb);

  // ---- conv2: tC = mean@W2 (dst-major); d_out = xb@root2 + bias2 + combine (f32) ----
  hipLaunchKernelGGL(gemm_rel_agg, relGrid, dim3(256), 0, stream,
                     xb, segrow, sorted_src, rowstart, perm, W2T, tC);
  hipLaunchKernelGGL((gemm_root_combine<false>), rootGrid, dim3(256), 0, stream,
                     xb, r2T, bias2, dstrow, tC, out, (ushort_t*)nullptr);
}